// Round 1
// baseline (211.426 us; speedup 1.0000x reference)
//
#include <hip/hip_runtime.h>
#include <math.h>

#define TOPK  20
#define NROW  4096
#define DDIM  256
#define NB    4
#define BLOCK 256
#define PT    (NROW / BLOCK)   // 16 elements per thread

__global__ __launch_bounds__(BLOCK) void fused_topk_gather(
    const float* __restrict__ src1,
    const float* __restrict__ src2,
    const float* __restrict__ mem,
    float* __restrict__ out)
{
    __shared__ float row[NROW];      // 16 KiB staged logits row
    __shared__ float red_f[4];       // per-wave reduce scratch (max, then sum)
    __shared__ float atop_v[4];      // per-wave argmax value
    __shared__ int   atop_i[4];      // per-wave argmax index
    __shared__ float w_lds[TOPK];    // winning softmax weights
    __shared__ int   i_lds[TOPK];    // winning indices

    const int n    = blockIdx.x;
    const int t    = threadIdx.x;
    const int wave = t >> 6;
    const int lane = t & 63;

    // ---- stage row (coalesced, stride BLOCK) + local max ----
    const float* mrow = mem + (size_t)n * NROW;
    float val[PT];
    float lmax = -INFINITY;
#pragma unroll
    for (int i = 0; i < PT; ++i) {
        float v = mrow[t + i * BLOCK];
        val[i] = v;
        row[t + i * BLOCK] = v;
        lmax = fmaxf(lmax, v);
    }
#pragma unroll
    for (int o = 32; o > 0; o >>= 1)
        lmax = fmaxf(lmax, __shfl_down(lmax, o, 64));
    if (lane == 0) red_f[wave] = lmax;
    __syncthreads();
    const float rowmax = fmaxf(fmaxf(red_f[0], red_f[1]), fmaxf(red_f[2], red_f[3]));

    // ---- sum of exp (registers only, then reduce) ----
    float lsum = 0.f;
#pragma unroll
    for (int i = 0; i < PT; ++i)
        lsum += __expf(val[i] - rowmax);
    __syncthreads();                 // protect red_f reuse (all read rowmax above)
#pragma unroll
    for (int o = 32; o > 0; o >>= 1)
        lsum += __shfl_down(lsum, o, 64);
    if (lane == 0) red_f[wave] = lsum;
    __syncthreads();
    const float inv_denom = 1.0f / (red_f[0] + red_f[1] + red_f[2] + red_f[3]);

    // ---- cached per-thread local argmax (tie -> lowest index via strict >) ----
    float cv = -INFINITY; int ci = t;
#pragma unroll
    for (int i = 0; i < PT; ++i) {
        if (val[i] > cv) { cv = val[i]; ci = t + i * BLOCK; }
    }

    // ---- 20 rounds of global argmax-extract ----
#pragma unroll 1
    for (int it = 0; it < TOPK; ++it) {
        float v = cv; int idx = ci;
#pragma unroll
        for (int o = 32; o > 0; o >>= 1) {
            float ov = __shfl_down(v, o, 64);
            int   oi = __shfl_down(idx, o, 64);
            if (ov > v || (ov == v && oi < idx)) { v = ov; idx = oi; }
        }
        if (lane == 0) { atop_v[wave] = v; atop_i[wave] = idx; }
        __syncthreads();
        // all threads redundantly pick the block winner (no broadcast barrier)
        float wv = atop_v[0]; int wi = atop_i[0];
#pragma unroll
        for (int w2 = 1; w2 < 4; ++w2) {
            float v2 = atop_v[w2]; int i2 = atop_i[w2];
            if (v2 > wv || (v2 == wv && i2 < wi)) { wv = v2; wi = i2; }
        }
        if (t == 0) {
            w_lds[it] = __expf(wv - rowmax) * inv_denom;
            i_lds[it] = wi;
        }
        // owner invalidates its element and rescans its own column set only
        if ((wi & (BLOCK - 1)) == t) {
            row[wi] = -INFINITY;
            cv = -INFINITY; ci = t;
#pragma unroll
            for (int ii = 0; ii < PT; ++ii) {
                float vv = row[t + ii * BLOCK];
                if (vv > cv) { cv = vv; ci = t + ii * BLOCK; }
            }
        }
        __syncthreads();
    }

    // ---- epilogue: out[b,n,:] = src1[b,n,:] + sum_k w_k * src2[b,idx_k,:] ----
    // wave = batch b (4 waves, NB==4); 64 lanes * float4 = 256 floats = DDIM
    const int b  = t >> 6;
    const int d4 = t & 63;
    const size_t bn = ((size_t)b * NROW + n) * (DDIM / 4) + d4;
    const float4* s2b = (const float4*)src2 + (size_t)b * NROW * (DDIM / 4) + d4;
    float4 acc = ((const float4*)src1)[bn];
#pragma unroll
    for (int k = 0; k < TOPK; ++k) {
        const float w = w_lds[k];
        const float4 g = s2b[(size_t)i_lds[k] * (DDIM / 4)];
        acc.x = fmaf(w, g.x, acc.x);
        acc.y = fmaf(w, g.y, acc.y);
        acc.z = fmaf(w, g.z, acc.z);
        acc.w = fmaf(w, g.w, acc.w);
    }
    ((float4*)out)[bn] = acc;
}

extern "C" void kernel_launch(void* const* d_in, const int* in_sizes, int n_in,
                              void* d_out, int out_size, void* d_ws, size_t ws_size,
                              hipStream_t stream) {
    const float* src1 = (const float*)d_in[0];   // [4, 4096, 256] f32
    const float* src2 = (const float*)d_in[1];   // [4, 4096, 256] f32
    const float* mem  = (const float*)d_in[2];   // [4096, 4096] f32
    float* out = (float*)d_out;                  // [4, 4096, 256] f32
    fused_topk_gather<<<NROW, BLOCK, 0, stream>>>(src1, src2, mem, out);
}

// Round 2
// 178.496 us; speedup vs baseline: 1.1845x; 1.1845x over previous
//
#include <hip/hip_runtime.h>
#include <math.h>

#define TOPK  20
#define NROW  4096
#define DDIM  256
#define NB    4
#define WPB   4                 // waves (rows) per block
#define BLOCK (WPB * 64)
#define NCHUNK 16               // float4 chunks per lane (64 values/lane)

struct WaveScratch {
    float cand_v[64];
    int   cand_i[64];
    float w[TOPK];
    int   idx[TOPK];
};

__device__ __forceinline__ void wave_lds_fence() {
    asm volatile("s_waitcnt lgkmcnt(0)" ::: "memory");
}

__device__ __forceinline__ bool lex_gt(float av, int ai, float bv, int bi) {
    // key = (value desc, index asc)
    return (av > bv) || (av == bv && ai < bi);
}

// bitonic sort 64 (v,i) pairs across lanes, descending by lex key
__device__ __forceinline__ void bitonic64_desc(float& v, int& i, int lane) {
#pragma unroll
    for (int k = 2; k <= 64; k <<= 1) {
#pragma unroll
        for (int j = k >> 1; j > 0; j >>= 1) {
            float pv = __shfl_xor(v, j, 64);
            int   pi = __shfl_xor(i, j, 64);
            bool takeBig = ((lane & k) == 0) == ((lane & j) == 0);
            bool pBig = lex_gt(pv, pi, v, i);
            if (takeBig == pBig) { v = pv; i = pi; }
        }
    }
}

__global__ __launch_bounds__(BLOCK, 4) void fused_topk_gather(
    const float* __restrict__ src1,
    const float* __restrict__ src2,
    const float* __restrict__ mem,
    float* __restrict__ out)
{
    __shared__ WaveScratch ws_all[WPB];
    const int wave = threadIdx.x >> 6;
    const int lane = threadIdx.x & 63;
    const int n    = blockIdx.x * WPB + wave;
    WaveScratch& ws = ws_all[wave];

    // ---- stage full row into registers: lane loads float4 at (lane + 64*j) ----
    // element index of (j, c) = 4*lane + 256*j + c
    const float4* mrow = (const float4*)(mem + (size_t)n * NROW);
    float4 v4[NCHUNK];
#pragma unroll
    for (int j = 0; j < NCHUNK; ++j) v4[j] = mrow[lane + 64 * j];

    // ---- per-lane top-1 (ascending index order -> strict > keeps lowest idx) ----
    float bv = -INFINITY; int bi = 0x7fffffff;
#pragma unroll
    for (int j = 0; j < NCHUNK; ++j) {
        const int base = 4 * lane + 256 * j;
        if (v4[j].x > bv) { bv = v4[j].x; bi = base + 0; }
        if (v4[j].y > bv) { bv = v4[j].y; bi = base + 1; }
        if (v4[j].z > bv) { bv = v4[j].z; bi = base + 2; }
        if (v4[j].w > bv) { bv = v4[j].w; bi = base + 3; }
    }

    // ---- sort the 64 lane-maxima; s[0] = row max; s[19] = threshold tau ----
    float sv = bv; int si = bi;
    bitonic64_desc(sv, si, lane);
    const float rowmax = __shfl(sv, 0, 64);
    const float tv     = __shfl(sv, 19, 64);
    const int   ti     = __shfl(si, 19, 64);

    // ---- softmax denominator ----
    float lsum = 0.f;
#pragma unroll
    for (int j = 0; j < NCHUNK; ++j) {
        lsum += __expf(v4[j].x - rowmax) + __expf(v4[j].y - rowmax)
              + __expf(v4[j].z - rowmax) + __expf(v4[j].w - rowmax);
    }
#pragma unroll
    for (int o = 32; o > 0; o >>= 1) lsum += __shfl_xor(lsum, o, 64);
    const float inv_denom = 1.0f / lsum;

    // ---- count candidates >=lex (tv, ti); guaranteed >= 20 total ----
    int cnt = 0;
#pragma unroll
    for (int j = 0; j < NCHUNK; ++j) {
        const int base = 4 * lane + 256 * j;
        cnt += (v4[j].x > tv) || (v4[j].x == tv && (base + 0) <= ti);
        cnt += (v4[j].y > tv) || (v4[j].y == tv && (base + 1) <= ti);
        cnt += (v4[j].z > tv) || (v4[j].z == tv && (base + 2) <= ti);
        cnt += (v4[j].w > tv) || (v4[j].w == tv && (base + 3) <= ti);
    }
    int incl = cnt;
#pragma unroll
    for (int o = 1; o < 64; o <<= 1) {
        int t = __shfl_up(incl, o, 64);
        if (lane >= o) incl += t;
    }
    const int total = __builtin_amdgcn_readfirstlane(__shfl(incl, 63, 64));

    if (total <= 64) {
        // ---- FAST PATH: compact candidates to LDS, sort once, take 20 ----
        int off = incl - cnt;
#pragma unroll
        for (int j = 0; j < NCHUNK; ++j) {
            const int base = 4 * lane + 256 * j;
            const float4 q = v4[j];
            if ((q.x > tv) || (q.x == tv && (base + 0) <= ti)) { ws.cand_v[off] = q.x; ws.cand_i[off] = base + 0; ++off; }
            if ((q.y > tv) || (q.y == tv && (base + 1) <= ti)) { ws.cand_v[off] = q.y; ws.cand_i[off] = base + 1; ++off; }
            if ((q.z > tv) || (q.z == tv && (base + 2) <= ti)) { ws.cand_v[off] = q.z; ws.cand_i[off] = base + 2; ++off; }
            if ((q.w > tv) || (q.w == tv && (base + 3) <= ti)) { ws.cand_v[off] = q.w; ws.cand_i[off] = base + 3; ++off; }
        }
        wave_lds_fence();
        float cv = -INFINITY; int ci = 0x7fffffff;
        if (lane < total) { cv = ws.cand_v[lane]; ci = ws.cand_i[lane]; }
        bitonic64_desc(cv, ci, lane);
        if (lane < TOPK) {
            ws.w[lane]   = __expf(cv - rowmax) * inv_denom;
            ws.idx[lane] = ci;
        }
    } else {
        // ---- SLOW PATH (p ~ 0): 20 rounds of wave argmax extraction ----
        unsigned long long dead = 0;
        float cv = bv; int ci = bi;
        for (int r = 0; r < TOPK; ++r) {
            float wv = cv; int wi = ci;
#pragma unroll
            for (int o = 32; o > 0; o >>= 1) {
                float ov = __shfl_xor(wv, o, 64);
                int   oi = __shfl_xor(wi, o, 64);
                if (lex_gt(ov, oi, wv, wi)) { wv = ov; wi = oi; }
            }
            if (lane == 0) {
                ws.w[r]   = __expf(wv - rowmax) * inv_denom;
                ws.idx[r] = wi;
            }
            if (ci == wi) {  // unique owner
                const int e = (((wi >> 8) & 15) << 2) | (wi & 3);
                dead |= (1ull << e);
                cv = -INFINITY; ci = 0x7fffffff;
#pragma unroll
                for (int j = 0; j < NCHUNK; ++j) {
                    const int base = 4 * lane + 256 * j;
                    if (!((dead >> (4 * j + 0)) & 1) && v4[j].x > cv) { cv = v4[j].x; ci = base + 0; }
                    if (!((dead >> (4 * j + 1)) & 1) && v4[j].y > cv) { cv = v4[j].y; ci = base + 1; }
                    if (!((dead >> (4 * j + 2)) & 1) && v4[j].z > cv) { cv = v4[j].z; ci = base + 2; }
                    if (!((dead >> (4 * j + 3)) & 1) && v4[j].w > cv) { cv = v4[j].w; ci = base + 3; }
                }
            }
        }
    }
    wave_lds_fence();

    // ---- gather epilogue: out[b,n,:] = src1[b,n,:] + sum_k w_k * src2[b,idx_k,:] ----
    float wk[TOPK]; int ik[TOPK];
#pragma unroll
    for (int k = 0; k < TOPK; ++k) { wk[k] = ws.w[k]; ik[k] = ws.idx[k]; }  // LDS broadcast

    const float4* s1 = (const float4*)src1;
    const float4* s2 = (const float4*)src2;
    float4*       o4 = (float4*)out;
#pragma unroll
    for (int b = 0; b < NB; ++b) {
        const size_t rowbase = ((size_t)b * NROW + n) * (DDIM / 4) + lane;
        float4 acc = s1[rowbase];
#pragma unroll
        for (int k = 0; k < TOPK; ++k) {
            const float4 g = s2[((size_t)b * NROW + ik[k]) * (DDIM / 4) + lane];
            acc.x = fmaf(wk[k], g.x, acc.x);
            acc.y = fmaf(wk[k], g.y, acc.y);
            acc.z = fmaf(wk[k], g.z, acc.z);
            acc.w = fmaf(wk[k], g.w, acc.w);
        }
        o4[rowbase] = acc;
    }
}

extern "C" void kernel_launch(void* const* d_in, const int* in_sizes, int n_in,
                              void* d_out, int out_size, void* d_ws, size_t ws_size,
                              hipStream_t stream) {
    const float* src1 = (const float*)d_in[0];   // [4, 4096, 256] f32
    const float* src2 = (const float*)d_in[1];   // [4, 4096, 256] f32
    const float* mem  = (const float*)d_in[2];   // [4096, 4096] f32
    float* out = (float*)d_out;                  // [4, 4096, 256] f32
    fused_topk_gather<<<NROW / WPB, BLOCK, 0, stream>>>(src1, src2, mem, out);
}

// Round 3
// 157.316 us; speedup vs baseline: 1.3440x; 1.1346x over previous
//
#include <hip/hip_runtime.h>
#include <math.h>

#define TOPK  20
#define NROW  4096
#define DDIM  256
#define NB    4
#define WPB   2                 // waves (rows) per block
#define BLOCK (WPB * 64)
#define NCHUNK 16               // float4 chunks per lane along the row

struct WaveScratch {
    float cand_v[64];
    int   cand_i[64];
    float w[TOPK];
    int   idx[TOPK];
    int   cnt;
};

__device__ __forceinline__ void wave_lds_fence() {
    asm volatile("s_waitcnt lgkmcnt(0)" ::: "memory");
}

__device__ __forceinline__ bool lex_gt(float av, int ai, float bv, int bi) {
    return (av > bv) || (av == bv && ai < bi);   // (value desc, index asc)
}

// bitonic sort of 64 (v,i) pairs across lanes, descending by lex key
__device__ __forceinline__ void bitonic64_desc(float& v, int& i, int lane) {
#pragma unroll
    for (int k = 2; k <= 64; k <<= 1) {
#pragma unroll
        for (int j = k >> 1; j > 0; j >>= 1) {
            float pv = __shfl_xor(v, j, 64);
            int   pi = __shfl_xor(i, j, 64);
            bool takeBig = ((lane & k) == 0) == ((lane & j) == 0);
            bool pBig = lex_gt(pv, pi, v, i);
            if (takeBig == pBig) { v = pv; i = pi; }
        }
    }
}

__global__ __launch_bounds__(BLOCK, 4) void fused_topk_gather(
    const float* __restrict__ src1,
    const float* __restrict__ src2,
    const float* __restrict__ mem,
    float* __restrict__ out)
{
    __shared__ WaveScratch ws_all[WPB];
    const int wave = threadIdx.x >> 6;
    const int lane = threadIdx.x & 63;
    const int n    = blockIdx.x * WPB + wave;
    WaveScratch& ws = ws_all[wave];

    if (lane == 0) ws.cnt = 0;

    const float4* mrow = (const float4*)(mem + (size_t)n * NROW);

    // ---- PASS 1: stream row, per-lane argmax only (no row residency) ----
    float bv = -INFINITY; int bi = 0x7fffffff;
#pragma unroll 4
    for (int j = 0; j < NCHUNK; ++j) {
        const float4 q = mrow[lane + 64 * j];
        const int base = 4 * lane + 256 * j;
        if (q.x > bv) { bv = q.x; bi = base + 0; }
        if (q.y > bv) { bv = q.y; bi = base + 1; }
        if (q.z > bv) { bv = q.z; bi = base + 2; }
        if (q.w > bv) { bv = q.w; bi = base + 3; }
    }

    // sort lane maxima: sorted[0] = row max, sorted[19] = threshold tau
    float sv = bv; int si = bi;
    bitonic64_desc(sv, si, lane);
    const float rowmax = __shfl(sv, 0, 64);
    const float tv     = __shfl(sv, 19, 64);
    const int   ti     = __shfl(si, 19, 64);
    wave_lds_fence();   // cnt=0 visible before atomics

    // ---- PASS 2: re-read row (L2/LLC-hot): exp-sum + compact candidates ----
    float lsum = 0.f;
#pragma unroll 4
    for (int j = 0; j < NCHUNK; ++j) {
        const float4 q = mrow[lane + 64 * j];
        const int base = 4 * lane + 256 * j;
        lsum += __expf(q.x - rowmax) + __expf(q.y - rowmax)
              + __expf(q.z - rowmax) + __expf(q.w - rowmax);
        if ((q.x > tv) || (q.x == tv && (base + 0) <= ti)) {
            int off = atomicAdd(&ws.cnt, 1);
            if (off < 64) { ws.cand_v[off] = q.x; ws.cand_i[off] = base + 0; }
        }
        if ((q.y > tv) || (q.y == tv && (base + 1) <= ti)) {
            int off = atomicAdd(&ws.cnt, 1);
            if (off < 64) { ws.cand_v[off] = q.y; ws.cand_i[off] = base + 1; }
        }
        if ((q.z > tv) || (q.z == tv && (base + 2) <= ti)) {
            int off = atomicAdd(&ws.cnt, 1);
            if (off < 64) { ws.cand_v[off] = q.z; ws.cand_i[off] = base + 2; }
        }
        if ((q.w > tv) || (q.w == tv && (base + 3) <= ti)) {
            int off = atomicAdd(&ws.cnt, 1);
            if (off < 64) { ws.cand_v[off] = q.w; ws.cand_i[off] = base + 3; }
        }
    }
#pragma unroll
    for (int o = 32; o > 0; o >>= 1) lsum += __shfl_xor(lsum, o, 64);
    const float inv_denom = 1.0f / lsum;

    wave_lds_fence();
    const int total = ws.cnt;

    if (total <= 64) {
        // ---- FAST PATH: sort candidates once, take top-20 ----
        float cv = -INFINITY; int ci = 0x7fffffff;
        if (lane < total) { cv = ws.cand_v[lane]; ci = ws.cand_i[lane]; }
        bitonic64_desc(cv, ci, lane);
        if (lane < TOPK) {
            ws.w[lane]   = __expf(cv - rowmax) * inv_denom;
            ws.idx[lane] = ci;
        }
    } else {
        // ---- SLOW PATH (p ~ 0): 20 rounds of extraction, re-reading row ----
        unsigned long long dead = 0;
        for (int r = 0; r < TOPK; ++r) {
            float cv = -INFINITY; int ci = 0x7fffffff;
#pragma unroll 4
            for (int j = 0; j < NCHUNK; ++j) {
                const float4 q = mrow[lane + 64 * j];
                const int base = 4 * lane + 256 * j;
                if (!((dead >> (4 * j + 0)) & 1) && q.x > cv) { cv = q.x; ci = base + 0; }
                if (!((dead >> (4 * j + 1)) & 1) && q.y > cv) { cv = q.y; ci = base + 1; }
                if (!((dead >> (4 * j + 2)) & 1) && q.z > cv) { cv = q.z; ci = base + 2; }
                if (!((dead >> (4 * j + 3)) & 1) && q.w > cv) { cv = q.w; ci = base + 3; }
            }
            float wv = cv; int wi = ci;
#pragma unroll
            for (int o = 32; o > 0; o >>= 1) {
                float ov = __shfl_xor(wv, o, 64);
                int   oi = __shfl_xor(wi, o, 64);
                if (lex_gt(ov, oi, wv, wi)) { wv = ov; wi = oi; }
            }
            if (lane == 0) {
                ws.w[r]   = __expf(wv - rowmax) * inv_denom;
                ws.idx[r] = wi;
            }
            if (ci == wi) {   // unique owner kills its element
                const int e = 4 * ((wi >> 8) & 15) + (wi & 3);
                dead |= (1ull << e);
            }
        }
    }
    wave_lds_fence();

    // ---- epilogue: out[b,n,:] = src1[b,n,:] + sum_k w_k * src2[b,idx_k,:] ----
    const float4* s1 = (const float4*)src1;
    const float4* s2 = (const float4*)src2;
    float4*       o4 = (float4*)out;
#pragma unroll
    for (int b = 0; b < NB; ++b) {
        const size_t rowbase = ((size_t)b * NROW + n) * (DDIM / 4) + lane;
        float4 acc = s1[rowbase];
#pragma unroll
        for (int k = 0; k < TOPK; ++k) {
            const float wk = ws.w[k];          // LDS broadcast read
            const int   ik = ws.idx[k];
            const float4 g = s2[((size_t)b * NROW + ik) * (DDIM / 4) + lane];
            acc.x = fmaf(wk, g.x, acc.x);
            acc.y = fmaf(wk, g.y, acc.y);
            acc.z = fmaf(wk, g.z, acc.z);
            acc.w = fmaf(wk, g.w, acc.w);
        }
        o4[rowbase] = acc;
    }
}

extern "C" void kernel_launch(void* const* d_in, const int* in_sizes, int n_in,
                              void* d_out, int out_size, void* d_ws, size_t ws_size,
                              hipStream_t stream) {
    const float* src1 = (const float*)d_in[0];   // [4, 4096, 256] f32
    const float* src2 = (const float*)d_in[1];   // [4, 4096, 256] f32
    const float* mem  = (const float*)d_in[2];   // [4096, 4096] f32
    float* out = (float*)d_out;                  // [4, 4096, 256] f32
    fused_topk_gather<<<NROW / WPB, BLOCK, 0, stream>>>(src1, src2, mem, out);
}